// Round 3
// baseline (147.014 us; speedup 1.0000x reference)
//
#include <hip/hip_runtime.h>
#include <math.h>

#define B_ROWS 4096
#define D_DIM  1024
static constexpr float TEMP = 0.2f;

typedef __attribute__((ext_vector_type(8))) short bf16x8;  // 8 bf16 (4 VGPRs)
typedef __attribute__((ext_vector_type(4))) float f32x4;

// RNE float -> bf16 bits
__device__ inline unsigned short f2bf(float f) {
    unsigned int u = __float_as_uint(f);
    u += 0x7fffu + ((u >> 16) & 1u);
    return (unsigned short)(u >> 16);
}

// async global->LDS, 16 B/lane; LDS dest = wave-uniform base + lane*16
__device__ inline void gload_lds16(const unsigned short* g, unsigned short* l) {
    __builtin_amdgcn_global_load_lds(
        (const __attribute__((address_space(1))) unsigned int*)g,
        (__attribute__((address_space(3))) unsigned int*)l,
        16, 0, 0);
}

// ws layout: w[0]=pos acc, w[1]=neg acc, w[2]=ticket(u32),
//            then Zi (4096x1024 bf16) at w+16, Zj after.

// Wave-per-row normalize+cast. Block 0 thread 0 also zeroes accumulators
// (safe: completes before simloss launches, stream order).
__global__ __launch_bounds__(256) void norm_cast_kernel(
        const float* __restrict__ emb_i, const float* __restrict__ emb_j,
        unsigned short* __restrict__ Zi, unsigned short* __restrict__ Zj,
        float* __restrict__ w) {
    const int tid = threadIdx.x;
    if (blockIdx.x == 0 && tid == 0) {
        w[0] = 0.0f; w[1] = 0.0f;
        ((unsigned int*)w)[2] = 0u;
    }
    const int wave = tid >> 6, lane = tid & 63;
    const int row = blockIdx.x * 4 + wave;          // 0..8191
    const float* src; unsigned short* dst; int r;
    if (row < B_ROWS) { src = emb_i; dst = Zi; r = row; }
    else              { src = emb_j; dst = Zj; r = row - B_ROWS; }

    const float4* p = (const float4*)(src + (size_t)r * D_DIM);
    float4 v0 = p[lane], v1 = p[64 + lane], v2 = p[128 + lane], v3 = p[192 + lane];
    float s = v0.x*v0.x + v0.y*v0.y + v0.z*v0.z + v0.w*v0.w
            + v1.x*v1.x + v1.y*v1.y + v1.z*v1.z + v1.w*v1.w
            + v2.x*v2.x + v2.y*v2.y + v2.z*v2.z + v2.w*v2.w
            + v3.x*v3.x + v3.y*v3.y + v3.z*v3.z + v3.w*v3.w;
    #pragma unroll
    for (int m = 1; m < 64; m <<= 1) s += __shfl_xor(s, m, 64);
    const float inv = 1.0f / fmaxf(sqrtf(s), 1e-12f);

    ushort4* q = (ushort4*)(dst + (size_t)r * D_DIM);
    ushort4 o0 = { f2bf(v0.x*inv), f2bf(v0.y*inv), f2bf(v0.z*inv), f2bf(v0.w*inv) };
    ushort4 o1 = { f2bf(v1.x*inv), f2bf(v1.y*inv), f2bf(v1.z*inv), f2bf(v1.w*inv) };
    ushort4 o2 = { f2bf(v2.x*inv), f2bf(v2.y*inv), f2bf(v2.z*inv), f2bf(v2.w*inv) };
    ushort4 o3 = { f2bf(v3.x*inv), f2bf(v3.y*inv), f2bf(v3.z*inv), f2bf(v3.w*inv) };
    q[lane] = o0; q[64 + lane] = o1; q[128 + lane] = o2; q[192 + lane] = o3;
}

// 128x128 tile, BK=64, 4 waves x (4x4 of 16x16x32 MFMA).
// LDS layout: row stride 64 shorts (128 B); within a row the 8 16B-pieces
// are XOR-swizzled: physical piece p = (logical_chunk c + (row&7)) & 7.
// Staging (global_load_lds writes at lane*16) compensates by fetching from
// swizzled *global* k-offset per lane. Kills the 8-way read bank conflicts.
__global__ __launch_bounds__(256, 4) void simloss_mfma_kernel(
        const unsigned short* __restrict__ Zi,
        const unsigned short* __restrict__ Zj,
        float* __restrict__ w, float* __restrict__ out) {
    __shared__ __align__(16) unsigned short lA[128 * 64];  // 16 KB (Zj tile)
    __shared__ __align__(16) unsigned short lB[128 * 64];  // 16 KB (Zi tile)
    __shared__ float rn[4], rp[4];

    const int tid  = threadIdx.x;
    const int lane = tid & 63;
    const int wave = tid >> 6;
    const int wy = wave >> 1, wx = wave & 1;
    const int rowBase = blockIdx.y * 128;   // a (Zj rows)
    const int colBase = blockIdx.x * 128;   // b (Zi rows)

    // --- staging: wave stages chunks 4w..4w+3 of each tile (chunk = 8 rows x 128B)
    const int lrow = lane >> 3;             // row within chunk, 0..7
    const int lp   = lane & 7;              // physical 16B piece it will land in
    const int lc   = (lp - lrow) & 7;       // logical k-chunk (swizzle inverse)
    const unsigned short* gA = Zj + (size_t)(rowBase + wave * 32 + lrow) * D_DIM + lc * 8;
    const unsigned short* gB = Zi + (size_t)(colBase + wave * 32 + lrow) * D_DIM + lc * 8;
    unsigned short* sA = lA + wave * 4 * 512;   // 512 shorts = 1 KB chunk
    unsigned short* sB = lB + wave * 4 * 512;

    // --- fragment bases: A row R = wy*64 + i*16 + (lane&15); R&7 == lane&7,
    // so physical piece is lane-constant: p0 (k-half 0), p1 = p0^4 (k-half 1).
    const int fr = lane & 15;
    const int p0 = ((lane >> 4) + (lane & 7)) & 7;
    const int p1 = (p0 + 4) & 7;
    const unsigned short* fA0 = lA + (wy * 64 + fr) * 64 + p0 * 8;
    const unsigned short* fA1 = lA + (wy * 64 + fr) * 64 + p1 * 8;
    const unsigned short* fB0 = lB + (wx * 64 + fr) * 64 + p0 * 8;
    const unsigned short* fB1 = lB + (wx * 64 + fr) * 64 + p1 * 8;

    f32x4 acc[4][4];
    #pragma unroll
    for (int i = 0; i < 4; ++i)
        #pragma unroll
        for (int j = 0; j < 4; ++j)
            acc[i][j] = (f32x4){0.f, 0.f, 0.f, 0.f};

    for (int k0 = 0; k0 < D_DIM; k0 += 64) {
        __syncthreads();                    // prior readers done
        #pragma unroll
        for (int ch = 0; ch < 4; ++ch) {
            gload_lds16(gA + ch * 8 * D_DIM, sA + ch * 512);
            gload_lds16(gB + ch * 8 * D_DIM, sB + ch * 512);
        }
        gA += 64; gB += 64;
        __syncthreads();                    // staging visible

        // k-half 0 (k0..k0+32)
        bf16x8 a[4], b[4];
        #pragma unroll
        for (int i = 0; i < 4; ++i) a[i] = *(const bf16x8*)(fA0 + i * 1024);
        #pragma unroll
        for (int j = 0; j < 4; ++j) b[j] = *(const bf16x8*)(fB0 + j * 1024);
        #pragma unroll
        for (int i = 0; i < 4; ++i)
            #pragma unroll
            for (int j = 0; j < 4; ++j)
                acc[i][j] = __builtin_amdgcn_mfma_f32_16x16x32_bf16(
                    a[i], b[j], acc[i][j], 0, 0, 0);
        // k-half 1 (k0+32..k0+64)
        #pragma unroll
        for (int i = 0; i < 4; ++i) a[i] = *(const bf16x8*)(fA1 + i * 1024);
        #pragma unroll
        for (int j = 0; j < 4; ++j) b[j] = *(const bf16x8*)(fB1 + j * 1024);
        #pragma unroll
        for (int i = 0; i < 4; ++i)
            #pragma unroll
            for (int j = 0; j < 4; ++j)
                acc[i][j] = __builtin_amdgcn_mfma_f32_16x16x32_bf16(
                    a[i], b[j], acc[i][j], 0, 0, 0);
    }

    // --- fused epilogue; C layout: row=(lane>>4)*4+r, col=lane&15
    const int cr = (lane >> 4) * 4;
    const int cc = lane & 15;
    float neg = 0.f, pos = 0.f;
    #pragma unroll
    for (int i = 0; i < 4; ++i) {
        const int abase = rowBase + wy * 64 + i * 16 + cr;
        #pragma unroll
        for (int j = 0; j < 4; ++j) {
            const int b = colBase + wx * 64 + j * 16 + cc;
            #pragma unroll
            for (int r = 0; r < 4; ++r) {
                const float x = acc[i][j][r] - TEMP;   // sim - T
                if (abase + r == b) pos += __logf(1.0f + __expf(-x));
                else                neg += __logf(1.0f + __expf(x));
            }
        }
    }
    #pragma unroll
    for (int off = 32; off > 0; off >>= 1) {
        neg += __shfl_down(neg, off, 64);
        pos += __shfl_down(pos, off, 64);
    }
    if (lane == 0) { rn[wave] = neg; rp[wave] = pos; }
    __syncthreads();
    if (tid == 0) {
        atomicAdd(&w[1], rn[0] + rn[1] + rn[2] + rn[3]);
        if (blockIdx.x == blockIdx.y)
            atomicAdd(&w[0], rp[0] + rp[1] + rp[2] + rp[3]);
        __threadfence();
        unsigned int done = atomicAdd(((unsigned int*)w) + 2, 1u);
        if (done == gridDim.x * gridDim.y - 1) {   // last block finalizes
            const float psum = atomicAdd(&w[0], 0.0f);
            const float nsum = atomicAdd(&w[1], 0.0f);
            out[0] = 0.5f * (psum / (float)B_ROWS)
                   + 0.5f * (nsum / ((float)B_ROWS * (float)(B_ROWS - 1)));
        }
    }
}

extern "C" void kernel_launch(void* const* d_in, const int* in_sizes, int n_in,
                              void* d_out, int out_size, void* d_ws, size_t ws_size,
                              hipStream_t stream) {
    const float* emb_i = (const float*)d_in[0];
    const float* emb_j = (const float*)d_in[1];
    float* w = (float*)d_ws;
    unsigned short* Zi = (unsigned short*)(w + 16);
    unsigned short* Zj = Zi + (size_t)B_ROWS * D_DIM;
    float* out = (float*)d_out;

    norm_cast_kernel<<<2 * B_ROWS / 4, 256, 0, stream>>>(emb_i, emb_j, Zi, Zj, w);
    dim3 grid(B_ROWS / 128, B_ROWS / 128);   // 32 x 32 = 1024 blocks
    simloss_mfma_kernel<<<grid, 256, 0, stream>>>(Zi, Zj, w, out);
}

// Round 4
// 125.859 us; speedup vs baseline: 1.1681x; 1.1681x over previous
//
#include <hip/hip_runtime.h>
#include <math.h>

#define B_ROWS 4096
#define D_DIM  1024
static constexpr float TEMP = 0.2f;

typedef __attribute__((ext_vector_type(8))) short bf16x8;  // 8 bf16 (4 VGPRs)
typedef __attribute__((ext_vector_type(4))) float f32x4;

// RNE float -> bf16 bits
__device__ inline unsigned short f2bf(float f) {
    unsigned int u = __float_as_uint(f);
    u += 0x7fffu + ((u >> 16) & 1u);
    return (unsigned short)(u >> 16);
}

// async global->LDS, 16 B/lane; LDS dest = wave-uniform base + lane*16
__device__ inline void gload_lds16(const unsigned short* g, unsigned short* l) {
    __builtin_amdgcn_global_load_lds(
        (const __attribute__((address_space(1))) unsigned int*)g,
        (__attribute__((address_space(3))) unsigned int*)l,
        16, 0, 0);
}

// ws layout: w[0]=pos acc, w[1]=neg acc, w[2]=ticket(u32),
//            then Zi (4096x1024 bf16) at w+16, Zj after.

// Wave-per-row normalize + bf16 cast; no block barriers.
__global__ __launch_bounds__(256) void norm_cast_kernel(
        const float* __restrict__ emb_i, const float* __restrict__ emb_j,
        unsigned short* __restrict__ Zi, unsigned short* __restrict__ Zj,
        float* __restrict__ w) {
    const int tid = threadIdx.x;
    if (blockIdx.x == 0 && tid == 0) {
        w[0] = 0.0f; w[1] = 0.0f;
        ((unsigned int*)w)[2] = 0u;
    }
    const int wave = tid >> 6, lane = tid & 63;
    const int row = blockIdx.x * 4 + wave;          // 0..8191
    const float* src; unsigned short* dst; int r;
    if (row < B_ROWS) { src = emb_i; dst = Zi; r = row; }
    else              { src = emb_j; dst = Zj; r = row - B_ROWS; }

    const float4* p = (const float4*)(src + (size_t)r * D_DIM);
    float4 v0 = p[lane], v1 = p[64 + lane], v2 = p[128 + lane], v3 = p[192 + lane];
    float s = v0.x*v0.x + v0.y*v0.y + v0.z*v0.z + v0.w*v0.w
            + v1.x*v1.x + v1.y*v1.y + v1.z*v1.z + v1.w*v1.w
            + v2.x*v2.x + v2.y*v2.y + v2.z*v2.z + v2.w*v2.w
            + v3.x*v3.x + v3.y*v3.y + v3.z*v3.z + v3.w*v3.w;
    #pragma unroll
    for (int m = 1; m < 64; m <<= 1) s += __shfl_xor(s, m, 64);
    const float inv = 1.0f / fmaxf(sqrtf(s), 1e-12f);

    ushort4* q = (ushort4*)(dst + (size_t)r * D_DIM);
    ushort4 o0 = { f2bf(v0.x*inv), f2bf(v0.y*inv), f2bf(v0.z*inv), f2bf(v0.w*inv) };
    ushort4 o1 = { f2bf(v1.x*inv), f2bf(v1.y*inv), f2bf(v1.z*inv), f2bf(v1.w*inv) };
    ushort4 o2 = { f2bf(v2.x*inv), f2bf(v2.y*inv), f2bf(v2.z*inv), f2bf(v2.w*inv) };
    ushort4 o3 = { f2bf(v3.x*inv), f2bf(v3.y*inv), f2bf(v3.z*inv), f2bf(v3.w*inv) };
    q[lane] = o0; q[64 + lane] = o1; q[128 + lane] = o2; q[192 + lane] = o3;
}

// 128x256 block tile, BK=32, 4 waves: wave (wy,wx) owns 64x128 = 4x8 MFMA
// tiles of 16x16x32. Grid 32x16 = 512 blocks = exactly 2 resident/CU.
//
// LDS: row stride 32 shorts (64 B = 4 x 16B pieces). XOR swizzle: the 16B
// piece holding logical k-chunk c of row R sits at physical piece
// p = (c + (R>>1)) & 3.  global_load_lds writes at wave-uniform base +
// lane*16, so staging fetches from the swizzled *global* k-offset.
// Fragment reads then hit each (row-parity, piece) bank slot exactly twice
// per 16-lane quad -> 2-way = conflict-free.
__global__ __launch_bounds__(256, 2) void simloss_mfma_kernel(
        const unsigned short* __restrict__ Zi,
        const unsigned short* __restrict__ Zj,
        float* __restrict__ w, float* __restrict__ out) {
    __shared__ __align__(16) unsigned short lA[128 * 32];  //  8 KB (Zj rows)
    __shared__ __align__(16) unsigned short lB[256 * 32];  // 16 KB (Zi rows)
    __shared__ float rn[4], rp[4];

    const int tid  = threadIdx.x;
    const int lane = tid & 63;
    const int wave = tid >> 6;
    const int wy = wave >> 1, wx = wave & 1;
    const int rowBase = blockIdx.y * 128;   // a (Zj rows)
    const int colBase = blockIdx.x * 256;   // b (Zi rows)

    // --- staging: chunk = 16 rows x 64 B = 1 KB. A has 8 chunks (wave: 2),
    //     B has 16 chunks (wave: 4).
    const int lrow = lane >> 2;             // 0..15 row within chunk
    const int lp   = lane & 3;              // physical 16B piece
    const int lc   = (lp - (lrow >> 1)) & 3;  // logical k-chunk (swizzle^-1)
    const unsigned short* gA0 = Zj + (size_t)(rowBase + (2*wave+0)*16 + lrow) * D_DIM + lc*8;
    const unsigned short* gA1 = Zj + (size_t)(rowBase + (2*wave+1)*16 + lrow) * D_DIM + lc*8;
    const unsigned short* gB0 = Zi + (size_t)(colBase + (4*wave+0)*16 + lrow) * D_DIM + lc*8;
    const unsigned short* gB1 = Zi + (size_t)(colBase + (4*wave+1)*16 + lrow) * D_DIM + lc*8;
    const unsigned short* gB2 = Zi + (size_t)(colBase + (4*wave+2)*16 + lrow) * D_DIM + lc*8;
    const unsigned short* gB3 = Zi + (size_t)(colBase + (4*wave+3)*16 + lrow) * D_DIM + lc*8;
    unsigned short* sA0 = lA + (2*wave+0) * 512;
    unsigned short* sA1 = lA + (2*wave+1) * 512;
    unsigned short* sB0 = lB + (4*wave+0) * 512;
    unsigned short* sB1 = lB + (4*wave+1) * 512;
    unsigned short* sB2 = lB + (4*wave+2) * 512;
    unsigned short* sB3 = lB + (4*wave+3) * 512;

    // --- fragment bases: row R = (sub)*16? + fr, physical piece
    //     p0 = (q + (fr>>1)) & 3 (independent of the 16-row tile index).
    const int fr = lane & 15;
    const int q4 = lane >> 4;
    const int p0 = (q4 + (fr >> 1)) & 3;
    const unsigned short* fA = lA + (wy * 64 + fr) * 32 + p0 * 8;
    const unsigned short* fB = lB + (wx * 128 + fr) * 32 + p0 * 8;

    f32x4 acc[4][8];
    #pragma unroll
    for (int i = 0; i < 4; ++i)
        #pragma unroll
        for (int j = 0; j < 8; ++j)
            acc[i][j] = (f32x4){0.f, 0.f, 0.f, 0.f};

    for (int k0 = 0; k0 < D_DIM; k0 += 32) {
        __syncthreads();                    // prior readers done
        gload_lds16(gA0, sA0); gload_lds16(gA1, sA1);
        gload_lds16(gB0, sB0); gload_lds16(gB1, sB1);
        gload_lds16(gB2, sB2); gload_lds16(gB3, sB3);
        gA0 += 32; gA1 += 32; gB0 += 32; gB1 += 32; gB2 += 32; gB3 += 32;
        __syncthreads();                    // staging visible

        bf16x8 a[4], b[8];
        #pragma unroll
        for (int i = 0; i < 4; ++i) a[i] = *(const bf16x8*)(fA + i * 16 * 32);
        #pragma unroll
        for (int j = 0; j < 8; ++j) b[j] = *(const bf16x8*)(fB + j * 16 * 32);
        #pragma unroll
        for (int i = 0; i < 4; ++i)
            #pragma unroll
            for (int j = 0; j < 8; ++j)
                acc[i][j] = __builtin_amdgcn_mfma_f32_16x16x32_bf16(
                    a[i], b[j], acc[i][j], 0, 0, 0);
    }

    // --- fused epilogue; C layout: row=(lane>>4)*4+r, col=lane&15
    const int cr = q4 * 4;
    const int cc = lane & 15;
    float neg = 0.f, pos = 0.f;
    #pragma unroll
    for (int i = 0; i < 4; ++i) {
        const int abase = rowBase + wy * 64 + i * 16 + cr;
        #pragma unroll
        for (int j = 0; j < 8; ++j) {
            const int b = colBase + wx * 128 + j * 16 + cc;
            #pragma unroll
            for (int r = 0; r < 4; ++r) {
                const float x = acc[i][j][r] - TEMP;   // sim - T
                if (abase + r == b) pos += __logf(1.0f + __expf(-x));
                else                neg += __logf(1.0f + __expf(x));
            }
        }
    }
    #pragma unroll
    for (int off = 32; off > 0; off >>= 1) {
        neg += __shfl_down(neg, off, 64);
        pos += __shfl_down(pos, off, 64);
    }
    if (lane == 0) { rn[wave] = neg; rp[wave] = pos; }
    __syncthreads();
    if (tid == 0) {
        atomicAdd(&w[1], rn[0] + rn[1] + rn[2] + rn[3]);
        if ((int)blockIdx.x == (int)(blockIdx.y >> 1))   // tile containing diagonal
            atomicAdd(&w[0], rp[0] + rp[1] + rp[2] + rp[3]);
        __threadfence();
        unsigned int done = atomicAdd(((unsigned int*)w) + 2, 1u);
        if (done == gridDim.x * gridDim.y - 1) {   // last block finalizes
            const float psum = atomicAdd(&w[0], 0.0f);
            const float nsum = atomicAdd(&w[1], 0.0f);
            out[0] = 0.5f * (psum / (float)B_ROWS)
                   + 0.5f * (nsum / ((float)B_ROWS * (float)(B_ROWS - 1)));
        }
    }
}

extern "C" void kernel_launch(void* const* d_in, const int* in_sizes, int n_in,
                              void* d_out, int out_size, void* d_ws, size_t ws_size,
                              hipStream_t stream) {
    const float* emb_i = (const float*)d_in[0];
    const float* emb_j = (const float*)d_in[1];
    float* w = (float*)d_ws;
    unsigned short* Zi = (unsigned short*)(w + 16);
    unsigned short* Zj = Zi + (size_t)B_ROWS * D_DIM;
    float* out = (float*)d_out;

    norm_cast_kernel<<<2 * B_ROWS / 4, 256, 0, stream>>>(emb_i, emb_j, Zi, Zj, w);
    dim3 grid(B_ROWS / 256, B_ROWS / 128);   // 16 x 32 = 512 blocks, 2/CU
    simloss_mfma_kernel<<<grid, 256, 0, stream>>>(Zi, Zj, w, out);
}